// Round 8
// baseline (315.106 us; speedup 1.0000x reference)
//
#include <hip/hip_runtime.h>

#define NPTS 262144
#define KVOL 27
#define NPAIRS 65536
#define TP (KVOL*NPAIRS)     // 1769472 pairs
#define CH 64
#define NT32 (NPTS/32)       // 8192 32-row output tiles
#define NSEG (NT32*32)       // 262144 segments (k padded to 32)
#define NBLK2 2048           // conv blocks (4 waves, each owns a 32-row tile)
#define MAXR 12              // max collision rounds; P(exceed) < 1e-9

typedef __attribute__((ext_vector_type(8))) short bf16x8;
typedef __attribute__((ext_vector_type(4))) float f32x4;

__device__ inline unsigned short f2bf(float x){
  unsigned int u = __float_as_uint(x);
  u += 0x7FFFu + ((u >> 16) & 1u);   // RNE
  return (unsigned short)(u >> 16);
}

__device__ inline bf16x8 pack8(float4 a, float4 b){
  bf16x8 r;
  r[0]=(short)f2bf(a.x); r[1]=(short)f2bf(a.y); r[2]=(short)f2bf(a.z); r[3]=(short)f2bf(a.w);
  r[4]=(short)f2bf(b.x); r[5]=(short)f2bf(b.y); r[6]=(short)f2bf(b.z); r[7]=(short)f2bf(b.w);
  return r;
}

// ---- fused: feat->bf16 (bf16 path), weight pack, count + rank capture ----
template<bool BF16G>
__global__ void k_pre(const float* __restrict__ feat, const float* __restrict__ w,
                      const int2* __restrict__ km, unsigned short* __restrict__ featb,
                      unsigned short* __restrict__ wpack, int* __restrict__ cnt,
                      unsigned short* __restrict__ rankb){
  int i = blockIdx.x*256 + threadIdx.x;
  if (BF16G){
    float4 v = ((const float4*)feat)[i];     // grid sized to NPTS*CH/4
    ushort4 r;
    r.x = f2bf(v.x); r.y = f2bf(v.y); r.z = f2bf(v.z); r.w = f2bf(v.w);
    ((ushort4*)featb)[i] = r;
  }
  if (i < TP){
    int2 io = km[i];
    int k = i >> 16;
    int seg = ((io.y >> 5) << 5) | k;
    int rank = atomicAdd(&cnt[seg], 1);
    rankb[i] = (unsigned short)rank;
  }
  if (i < KVOL*CH*CH){
    int j = i & 7, col = (i >> 3) & 63, kb = (i >> 9) & 7, k = i >> 12;
    wpack[i] = f2bf(w[(k*CH + kb*8 + j)*CH + col]);
  }
}

// ---- assign contiguous record ranges per segment (order-free, no scan) ----
__global__ void k_assign(const int* __restrict__ cnt, int* __restrict__ gtot,
                         int2* __restrict__ segd){
  int i = blockIdx.x*256 + threadIdx.x;   // NSEG
  int l = threadIdx.x & 63;
  int c = cnt[i];
  int v = c;
  #pragma unroll
  for (int d = 1; d < 64; d <<= 1){ int u = __shfl_up(v, d, 64); if (l >= d) v += u; }
  int wtot = __shfl(v, 63, 64);
  int base = 0;
  if (l == 63) base = atomicAdd(gtot, wtot);
  base = __shfl(base, 63, 64);
  segd[i] = make_int2(base + v - c, c);
}

// ---- scatter packed records (in:18b | slot:5b) via stored rank, no atomics ----
__global__ void k_scatter(const int2* __restrict__ km, const unsigned short* __restrict__ rankb,
                          const int2* __restrict__ segd, int* __restrict__ records){
  int i = blockIdx.x*256 + threadIdx.x;
  int2 io = km[i];
  int k = i >> 16;
  int seg = ((io.y >> 5) << 5) | k;
  int pos = segd[seg].x + rankb[i];
  records[pos] = io.x | ((io.y & 31) << 18);
}

// ---- conv: wave owns 32 rows; reg acc; LDS slot table; paired-round gathers ----
template<bool BF16G>
__global__ __launch_bounds__(256, 4) void k_conv8(
    const unsigned short* __restrict__ featb, const float* __restrict__ featf,
    const unsigned short* __restrict__ wpack, const int* __restrict__ records,
    const int2* __restrict__ segd, float* __restrict__ out, float* __restrict__ partials)
{
  __shared__ int lcnt[4][32];
  __shared__ int lslot[4][MAXR*32];
  __shared__ float sred[4][2][64];

  int tid = threadIdx.x;
  int wv = tid>>6, l = tid&63, lg = l>>4, li = l&15;
  int t32 = blockIdx.x*4 + wv;      // 32-row tile
  int segbase = t32 << 5;

  const bf16x8* fb = (const bf16x8*)featb;
  const float4* ff = (const float4*)featf;
  // per-lane B base: vec index (h*4+lg)*64 + ct*16 + li; k advances by 512 vecs
  const bf16x8* wbase = ((const bf16x8*)wpack) + lg*64 + li;

  f32x4 acc[2][4];
  #pragma unroll
  for (int rt = 0; rt < 2; rt++)
    #pragma unroll
    for (int ct = 0; ct < 4; ct++) acc[rt][ct] = (f32x4)(0.0f);

  int2 sd  = segd[segbase];
  int2 sd1 = segd[segbase + 1];
  int rec_pf = 0;
  if (l < sd.y) rec_pf = records[sd.x + l];

  for (int k = 0; k < KVOL; k++){
    int2 sd2 = segd[segbase + min(k + 2, 31)];
    int rec_nx = 0;
    if (l < sd1.y) rec_nx = records[sd1.x + l];   // prefetch next k's first chunk

    int beg = sd.x, tot = sd.y;
    if (tot > 0){
      // B fragments for offset k
      bf16x8 B[4][2];
      #pragma unroll
      for (int ct = 0; ct < 4; ct++)
        #pragma unroll
        for (int h = 0; h < 2; h++)
          B[ct][h] = wbase[k*512 + h*256 + ct*16];

      int rec = rec_pf;
      for (int c0 = 0; c0 < tot; c0 += 64){
        int cc = min(64, tot - c0);
        if (c0 > 0 && l < cc) rec = records[beg + c0 + l];  // rare slow path
        if (l < 32) lcnt[wv][l] = 0;
        if (l < cc){
          int slot = (rec >> 18) & 31;
          int rank = atomicAdd(&lcnt[wv][slot], 1);
          if (rank < MAXR) lslot[wv][rank*32 + slot] = rec;
        }
        int cnt0 = min(lcnt[wv][li], MAXR);
        int cnt1 = min(lcnt[wv][16 + li], MAXR);
        int nr = max(cnt0, cnt1);
        #pragma unroll
        for (int d = 1; d < 16; d <<= 1) nr = max(nr, __shfl_xor(nr, d, 64));
        // nr is wave-uniform (values identical across lane groups)

        for (int rb = 0; rb < nr; rb += 2){
          int recA0 = lslot[wv][rb*32 + li];
          int recA1 = lslot[wv][rb*32 + 16 + li];
          int recB0 = lslot[wv][min(rb+1, MAXR-1)*32 + li];
          int recB1 = lslot[wv][min(rb+1, MAXR-1)*32 + 16 + li];
          bool vA0 = (rb < cnt0), vA1 = (rb < cnt1);
          bool vB0 = (rb+1 < cnt0), vB1 = (rb+1 < cnt1);
          // batched gathers for both rounds (up to 8 concurrent 16B loads)
          bf16x8 a00 = (bf16x8)(short)0, a01 = (bf16x8)(short)0;
          bf16x8 a10 = (bf16x8)(short)0, a11 = (bf16x8)(short)0;
          bf16x8 b00 = (bf16x8)(short)0, b01 = (bf16x8)(short)0;
          bf16x8 b10 = (bf16x8)(short)0, b11 = (bf16x8)(short)0;
          if (vA0){
            int in = recA0 & 0x3FFFF;
            if (BF16G){ a00 = fb[in*8 + lg]; a01 = fb[in*8 + 4 + lg]; }
            else {
              float4 u0 = ff[in*16 + lg*2],     u1 = ff[in*16 + lg*2 + 1];
              float4 u2 = ff[in*16 + 8 + lg*2], u3 = ff[in*16 + 8 + lg*2 + 1];
              a00 = pack8(u0, u1); a01 = pack8(u2, u3);
            }
          }
          if (vA1){
            int in = recA1 & 0x3FFFF;
            if (BF16G){ a10 = fb[in*8 + lg]; a11 = fb[in*8 + 4 + lg]; }
            else {
              float4 u0 = ff[in*16 + lg*2],     u1 = ff[in*16 + lg*2 + 1];
              float4 u2 = ff[in*16 + 8 + lg*2], u3 = ff[in*16 + 8 + lg*2 + 1];
              a10 = pack8(u0, u1); a11 = pack8(u2, u3);
            }
          }
          if (vB0){
            int in = recB0 & 0x3FFFF;
            if (BF16G){ b00 = fb[in*8 + lg]; b01 = fb[in*8 + 4 + lg]; }
            else {
              float4 u0 = ff[in*16 + lg*2],     u1 = ff[in*16 + lg*2 + 1];
              float4 u2 = ff[in*16 + 8 + lg*2], u3 = ff[in*16 + 8 + lg*2 + 1];
              b00 = pack8(u0, u1); b01 = pack8(u2, u3);
            }
          }
          if (vB1){
            int in = recB1 & 0x3FFFF;
            if (BF16G){ b10 = fb[in*8 + lg]; b11 = fb[in*8 + 4 + lg]; }
            else {
              float4 u0 = ff[in*16 + lg*2],     u1 = ff[in*16 + lg*2 + 1];
              float4 u2 = ff[in*16 + 8 + lg*2], u3 = ff[in*16 + 8 + lg*2 + 1];
              b10 = pack8(u0, u1); b11 = pack8(u2, u3);
            }
          }
          // round rb
          if (__ballot(vA0)){
            #pragma unroll
            for (int ct = 0; ct < 4; ct++){
              acc[0][ct] = __builtin_amdgcn_mfma_f32_16x16x32_bf16(a00, B[ct][0], acc[0][ct], 0, 0, 0);
              acc[0][ct] = __builtin_amdgcn_mfma_f32_16x16x32_bf16(a01, B[ct][1], acc[0][ct], 0, 0, 0);
            }
          }
          if (__ballot(vA1)){
            #pragma unroll
            for (int ct = 0; ct < 4; ct++){
              acc[1][ct] = __builtin_amdgcn_mfma_f32_16x16x32_bf16(a10, B[ct][0], acc[1][ct], 0, 0, 0);
              acc[1][ct] = __builtin_amdgcn_mfma_f32_16x16x32_bf16(a11, B[ct][1], acc[1][ct], 0, 0, 0);
            }
          }
          // round rb+1
          if (rb + 1 < nr){
            if (__ballot(vB0)){
              #pragma unroll
              for (int ct = 0; ct < 4; ct++){
                acc[0][ct] = __builtin_amdgcn_mfma_f32_16x16x32_bf16(b00, B[ct][0], acc[0][ct], 0, 0, 0);
                acc[0][ct] = __builtin_amdgcn_mfma_f32_16x16x32_bf16(b01, B[ct][1], acc[0][ct], 0, 0, 0);
              }
            }
            if (__ballot(vB1)){
              #pragma unroll
              for (int ct = 0; ct < 4; ct++){
                acc[1][ct] = __builtin_amdgcn_mfma_f32_16x16x32_bf16(b10, B[ct][0], acc[1][ct], 0, 0, 0);
                acc[1][ct] = __builtin_amdgcn_mfma_f32_16x16x32_bf16(b11, B[ct][1], acc[1][ct], 0, 0, 0);
              }
            }
          }
        }
      }
    }
    rec_pf = rec_nx; sd = sd1; sd1 = sd2;
  }

  // flush 32x64 rows from registers
  #pragma unroll
  for (int rt = 0; rt < 2; rt++)
    #pragma unroll
    for (int r = 0; r < 4; r++){
      int row = t32*32 + rt*16 + lg*4 + r;
      #pragma unroll
      for (int ct = 0; ct < 4; ct++)
        out[row*CH + ct*16 + li] = acc[rt][ct][r];
    }

  // BN stats partials
  float s1[4], s2[4];
  #pragma unroll
  for (int ct = 0; ct < 4; ct++){
    float a1 = 0.f, a2 = 0.f;
    #pragma unroll
    for (int rt = 0; rt < 2; rt++)
      #pragma unroll
      for (int r = 0; r < 4; r++){
        float v = acc[rt][ct][r];
        a1 += v; a2 += v*v;
      }
    a1 += __shfl_xor(a1, 16, 64); a1 += __shfl_xor(a1, 32, 64);
    a2 += __shfl_xor(a2, 16, 64); a2 += __shfl_xor(a2, 32, 64);
    s1[ct] = a1; s2[ct] = a2;
  }
  __syncthreads();
  if (l < 16){
    #pragma unroll
    for (int ct = 0; ct < 4; ct++){
      sred[wv][0][ct*16 + li] = s1[ct];
      sred[wv][1][ct*16 + li] = s2[ct];
    }
  }
  __syncthreads();
  if (tid < 128){
    int h = tid >> 6, c = tid & 63;
    float p = sred[0][h][c] + sred[1][h][c] + sred[2][h][c] + sred[3][h][c];
    partials[blockIdx.x*128 + tid] = p;
  }
}

// ---- parallel final stats reduce ----
__global__ void k_statred(const float* __restrict__ partials, float* __restrict__ stats){
  __shared__ float sm_[256];
  int c = blockIdx.x;       // 0..127
  int t = threadIdx.x;      // 256
  float s = 0.f;
  for (int b = t; b < NBLK2; b += 256) s += partials[b*128 + c];
  sm_[t] = s;
  __syncthreads();
  for (int d = 128; d > 0; d >>= 1){
    if (t < d) sm_[t] += sm_[t+d];
    __syncthreads();
  }
  if (t == 0) stats[c] = sm_[0];
}

// ---- BN (batch stats, biased var) + ReLU, in place ----
__global__ void k_bn(float* __restrict__ out, const float* __restrict__ stats,
                     const float* __restrict__ g, const float* __restrict__ b){
  int i = blockIdx.x * blockDim.x + threadIdx.x;  // NPTS*CH/4
  float4 v = ((const float4*)out)[i];
  int c0 = (i * 4) & 63;
  float vals[4] = {v.x, v.y, v.z, v.w};
  float res[4];
  #pragma unroll
  for (int q = 0; q < 4; q++){
    int c = c0 + q;
    float mean = stats[c] * (1.0f/NPTS);
    float var  = stats[64+c] * (1.0f/NPTS) - mean*mean;
    float inv  = rsqrtf(var + 1e-5f);
    float y = (vals[q] - mean) * inv * g[c] + b[c];
    res[q] = fmaxf(y, 0.0f);
  }
  float4 r; r.x=res[0]; r.y=res[1]; r.z=res[2]; r.w=res[3];
  ((float4*)out)[i] = r;
}

extern "C" void kernel_launch(void* const* d_in, const int* in_sizes, int n_in,
                              void* d_out, int out_size, void* d_ws, size_t ws_size,
                              hipStream_t stream) {
  const float* feat   = (const float*)d_in[0];
  const int*   kmap   = (const int*)d_in[3];
  const float* weight = (const float*)d_in[4];
  const float* bnw    = (const float*)d_in[5];
  const float* bnb    = (const float*)d_in[6];
  float* out = (float*)d_out;

  char* ws = (char*)d_ws;
  size_t cur = 0;
  auto take = [&](size_t bytes){
    cur = (cur + 255) & ~(size_t)255;
    size_t p = cur; cur += bytes; return p;
  };
  float* stats          = (float*)(ws + take(2*CH*sizeof(float)));
  float* partials       = (float*)(ws + take((size_t)NBLK2*128*sizeof(float)));
  int* cnt              = (int*)(ws + take((size_t)(NSEG+64)*4));   // cnt + cursor at [NSEG]
  int2* segd            = (int2*)(ws + take((size_t)NSEG*8));
  unsigned short* wpack = (unsigned short*)(ws + take((size_t)KVOL*CH*CH*2));
  unsigned short* rankb = (unsigned short*)(ws + take((size_t)TP*2));
  int* records          = (int*)(ws + take((size_t)TP*4));
  size_t featb_off      = take((size_t)NPTS*CH*2);
  bool useBf16 = (ws_size >= cur);
  unsigned short* featb = (unsigned short*)(ws + featb_off);
  int* gtot = cnt + NSEG;

  hipMemsetAsync(cnt, 0, (size_t)(NSEG+64)*4, stream);

  const int2* km = (const int2*)kmap;
  if (useBf16)
    k_pre<true><<<NPTS*CH/4/256, 256, 0, stream>>>(feat, weight, km, featb, wpack, cnt, rankb);
  else
    k_pre<false><<<TP/256, 256, 0, stream>>>(feat, weight, km, featb, wpack, cnt, rankb);

  k_assign<<<NSEG/256, 256, 0, stream>>>(cnt, gtot, segd);
  k_scatter<<<TP/256, 256, 0, stream>>>(km, rankb, segd, records);

  if (useBf16)
    k_conv8<true><<<NBLK2, 256, 0, stream>>>(featb, feat, wpack, records, segd, out, partials);
  else
    k_conv8<false><<<NBLK2, 256, 0, stream>>>(featb, feat, wpack, records, segd, out, partials);

  k_statred<<<128, 256, 0, stream>>>(partials, stats);
  k_bn<<<NPTS*CH/4/256, 256, 0, stream>>>(out, stats, bnw, bnb);
}